// Round 1
// baseline (175.324 us; speedup 1.0000x reference)
//
#include <hip/hip_runtime.h>
#include <hip/hip_bf16.h>
#include <stdint.h>

#define NNODES  1000000
#define INDIM   128
#define HIDDIM  256
#define NCLSN   47
#define N0SZ    1171456
#define N1SZ    45056
#define N2SZ    4096
#define F0SZ    25
#define F1SZ    10

typedef __attribute__((ext_vector_type(8))) short short8;
typedef __attribute__((ext_vector_type(4))) float f32x4;

__device__ inline unsigned short f2bfu(float x) {
    __hip_bfloat16 h = __float2bfloat16(x);
    union { __hip_bfloat16 h; unsigned short u; } cv; cv.h = h; return cv.u;
}

// ---------------------------------------------------------------------------
// Kernel 1: layer-0 gather + mean.  X0[i] = [ mean_f node_feat[gid0[col0[i*25+f]]] (128) | node_feat[gid0[i]] (128) ]  as bf16
// 8 dst rows per block, 32 threads per row (float4 over 128 dims).
// ---------------------------------------------------------------------------
__global__ __launch_bounds__(256) void gather0_kernel(
    const float* __restrict__ node_feat, const int* __restrict__ gid0,
    const int* __restrict__ col0, __hip_bfloat16* __restrict__ X0) {
    __shared__ int sg[8 * F0SZ];
    __shared__ int sself[8];
    const int tid = threadIdx.x;
    const int rowbase = blockIdx.x * 8;
    if (tid < 8 * F0SZ) {
        int i = rowbase + tid / F0SZ;
        int f = tid % F0SZ;
        sg[tid] = gid0[col0[(size_t)i * F0SZ + f]];
    }
    if (tid < 8) sself[tid] = gid0[rowbase + tid];
    __syncthreads();
    const int r = tid >> 5;     // row in block 0..7
    const int c = tid & 31;     // float4 index 0..31
    const int i = rowbase + r;
    float4 acc = make_float4(0.f, 0.f, 0.f, 0.f);
    #pragma unroll
    for (int f = 0; f < F0SZ; ++f) {
        int g = sg[r * F0SZ + f];
        float4 v = ((const float4*)(node_feat + (size_t)g * INDIM))[c];
        acc.x += v.x; acc.y += v.y; acc.z += v.z; acc.w += v.w;
    }
    float4 sv = ((const float4*)(node_feat + (size_t)sself[r] * INDIM))[c];
    const float s = 1.0f / F0SZ;
    unsigned short* out = (unsigned short*)(X0 + (size_t)i * (2 * INDIM));
    ushort4 m, se;
    m.x = f2bfu(acc.x * s); m.y = f2bfu(acc.y * s); m.z = f2bfu(acc.z * s); m.w = f2bfu(acc.w * s);
    se.x = f2bfu(sv.x); se.y = f2bfu(sv.y); se.z = f2bfu(sv.z); se.w = f2bfu(sv.w);
    ((ushort4*)out)[c] = m;                       // dims [0,128)
    ((ushort4*)(out + INDIM))[c] = se;            // dims [128,256)
}

// ---------------------------------------------------------------------------
// Kernel 2: weight prep — bf16, transposed to [N][K] so B-fragments are 16B-contiguous.
// W0T: [256 n][256 k]  (k<128 -> Wn0, else Wr0).  W1T: [48 n][512 k] (n>=47 zero).
// ---------------------------------------------------------------------------
__global__ __launch_bounds__(256) void prep_w_kernel(
    const float* __restrict__ Wn0, const float* __restrict__ Wr0,
    const float* __restrict__ Wn1, const float* __restrict__ Wr1,
    __hip_bfloat16* __restrict__ W0T, __hip_bfloat16* __restrict__ W1T) {
    int tid = blockIdx.x * 256 + threadIdx.x;
    if (tid < 256 * 256) {
        int n = tid >> 8, k = tid & 255;
        float v = (k < INDIM) ? Wn0[(size_t)k * HIDDIM + n] : Wr0[(size_t)(k - INDIM) * HIDDIM + n];
        W0T[(size_t)n * 256 + k] = __float2bfloat16(v);
    }
    if (tid < 48 * 512) {
        int n = tid / 512, k = tid % 512;
        float v = 0.f;
        if (n < NCLSN) v = (k < HIDDIM) ? Wn1[(size_t)k * NCLSN + n] : Wr1[(size_t)(k - HIDDIM) * NCLSN + n];
        W1T[(size_t)n * 512 + k] = __float2bfloat16(v);
    }
}

// ---------------------------------------------------------------------------
// Kernel 3: layer-0 GEMM  H = relu(X0 @ W0 + b0), bf16 out.
// M=45056, N=256, K=256. Block = 4 waves sharing one 16-row M-tile;
// wave w covers N columns [w*64, w*64+64). A/B frags loaded straight from
// global (A: 16 full cachelines/wave-instr; B: L2-resident 128KB).
// ---------------------------------------------------------------------------
__global__ __launch_bounds__(256) void gemm0_kernel(
    const __hip_bfloat16* __restrict__ X0, const __hip_bfloat16* __restrict__ W0T,
    const float* __restrict__ b0, __hip_bfloat16* __restrict__ H) {
    const int wid = threadIdx.x >> 6;
    const int lane = threadIdx.x & 63;
    const int l15 = lane & 15;
    const int g = lane >> 4;
    const int row0 = blockIdx.x * 16;
    const int nbase = wid * 64;
    const short* A = (const short*)X0;
    const short* B = (const short*)W0T;
    f32x4 acc[4] = {};
    #pragma unroll
    for (int kk = 0; kk < 256; kk += 32) {
        const int ka = kk + g * 8;
        short8 a = *(const short8*)(A + (size_t)(row0 + l15) * 256 + ka);
        #pragma unroll
        for (int nt = 0; nt < 4; ++nt) {
            short8 b = *(const short8*)(B + (size_t)(nbase + nt * 16 + l15) * 256 + ka);
            acc[nt] = __builtin_amdgcn_mfma_f32_16x16x32_bf16(a, b, acc[nt], 0, 0, 0);
        }
    }
    #pragma unroll
    for (int nt = 0; nt < 4; ++nt) {
        const int col = nbase + nt * 16 + l15;
        const float bias = b0[col];
        #pragma unroll
        for (int r = 0; r < 4; ++r) {
            const int rr = row0 + g * 4 + r;
            float v = acc[nt][r] + bias;
            v = v > 0.f ? v : 0.f;
            H[(size_t)rr * HIDDIM + col] = __float2bfloat16(v);
        }
    }
}

// ---------------------------------------------------------------------------
// Kernel 4: layer-1 aggregation. X1[i] = [ mean_f H[col1[i*10+f]] (256) | H[i] (256) ]  bf16
// ---------------------------------------------------------------------------
__global__ __launch_bounds__(256) void agg1_kernel(
    const __hip_bfloat16* __restrict__ H, const int* __restrict__ col1,
    __hip_bfloat16* __restrict__ X1) {
    const int i = blockIdx.x;
    const int d = threadIdx.x;
    __shared__ int sc[F1SZ];
    if (d < F1SZ) sc[d] = col1[(size_t)i * F1SZ + d];
    __syncthreads();
    float acc = 0.f;
    #pragma unroll
    for (int f = 0; f < F1SZ; ++f)
        acc += __bfloat162float(H[(size_t)sc[f] * HIDDIM + d]);
    X1[(size_t)i * 512 + d] = __float2bfloat16(acc * (1.0f / F1SZ));
    X1[(size_t)i * 512 + 256 + d] = H[(size_t)i * HIDDIM + d];
}

// ---------------------------------------------------------------------------
// Kernel 5: layer-1 GEMM  out = X1 @ W1 + b1, fp32 out.
// M=4096, N=48(47), K=512. Block = 4 waves on ONE 16-row M-tile, 4-way K-split
// (each wave K-range of 128), LDS reduction. Grid = 256 blocks.
// ---------------------------------------------------------------------------
__global__ __launch_bounds__(256) void gemm1_kernel(
    const __hip_bfloat16* __restrict__ X1, const __hip_bfloat16* __restrict__ W1T,
    const float* __restrict__ b1, float* __restrict__ out) {
    __shared__ float red[4][16 * 48];
    const int wid = threadIdx.x >> 6;
    const int lane = threadIdx.x & 63;
    const int l15 = lane & 15;
    const int g = lane >> 4;
    const int row0 = blockIdx.x * 16;
    const short* A = (const short*)X1;
    const short* B = (const short*)W1T;
    f32x4 acc[3] = {};
    const int kbase = wid * 128;
    #pragma unroll
    for (int ks = 0; ks < 4; ++ks) {
        const int ka = kbase + ks * 32 + g * 8;
        short8 a = *(const short8*)(A + (size_t)(row0 + l15) * 512 + ka);
        #pragma unroll
        for (int nt = 0; nt < 3; ++nt) {
            short8 b = *(const short8*)(B + (size_t)(nt * 16 + l15) * 512 + ka);
            acc[nt] = __builtin_amdgcn_mfma_f32_16x16x32_bf16(a, b, acc[nt], 0, 0, 0);
        }
    }
    #pragma unroll
    for (int nt = 0; nt < 3; ++nt)
        #pragma unroll
        for (int r = 0; r < 4; ++r)
            red[wid][(g * 4 + r) * 48 + nt * 16 + l15] = acc[nt][r];
    __syncthreads();
    for (int t = threadIdx.x; t < 16 * 48; t += 256) {
        int r = t / 48, c = t % 48;
        if (c < NCLSN) {
            float v = red[0][t] + red[1][t] + red[2][t] + red[3][t] + b1[c];
            out[(size_t)(row0 + r) * NCLSN + c] = v;
        }
    }
}

// ---------------------------------------------------------------------------
extern "C" void kernel_launch(void* const* d_in, const int* in_sizes, int n_in,
                              void* d_out, int out_size, void* d_ws, size_t ws_size,
                              hipStream_t stream) {
    const float* node_feat = (const float*)d_in[0];
    const int*   gid0      = (const int*)d_in[1];
    const int*   col0      = (const int*)d_in[2];
    const int*   col1      = (const int*)d_in[3];
    const float* Wn0       = (const float*)d_in[4];
    const float* Wr0       = (const float*)d_in[5];
    const float* b0        = (const float*)d_in[6];
    const float* Wn1       = (const float*)d_in[7];
    const float* Wr1       = (const float*)d_in[8];
    const float* b1        = (const float*)d_in[9];

    char* ws = (char*)d_ws;
    // ws layout (256B-aligned):
    //   X0  bf16 [45056, 256] : 23,068,672 B
    //   H   bf16 [45056, 256] : 23,068,672 B
    //   X1  bf16 [ 4096, 512] :  4,194,304 B
    //   W0T bf16 [256, 256]   :    131,072 B
    //   W1T bf16 [ 48, 512]   :     49,152 B   (total ~50.5 MB)
    __hip_bfloat16* X0  = (__hip_bfloat16*)(ws);
    __hip_bfloat16* H   = (__hip_bfloat16*)(ws + 23068672);
    __hip_bfloat16* X1  = (__hip_bfloat16*)(ws + 46137344);
    __hip_bfloat16* W0T = (__hip_bfloat16*)(ws + 50331648);
    __hip_bfloat16* W1T = (__hip_bfloat16*)(ws + 50462720);
    float* out = (float*)d_out;

    hipLaunchKernelGGL(prep_w_kernel, dim3(256), dim3(256), 0, stream,
                       Wn0, Wr0, Wn1, Wr1, W0T, W1T);
    hipLaunchKernelGGL(gather0_kernel, dim3(N1SZ / 8), dim3(256), 0, stream,
                       node_feat, gid0, col0, X0);
    hipLaunchKernelGGL(gemm0_kernel, dim3(N1SZ / 16), dim3(256), 0, stream,
                       X0, W0T, b0, H);
    hipLaunchKernelGGL(agg1_kernel, dim3(N2SZ), dim3(256), 0, stream,
                       H, col1, X1);
    hipLaunchKernelGGL(gemm1_kernel, dim3(N2SZ / 16), dim3(256), 0, stream,
                       X1, W1T, b1, out);
}

// Round 4
// 144.129 us; speedup vs baseline: 1.2164x; 1.2164x over previous
//
#include <hip/hip_runtime.h>
#include <hip/hip_bf16.h>
#include <stdint.h>

#define NNODES  1000000
#define INDIM   128
#define HIDDIM  256
#define NCLSN   47
#define N0SZ    1171456
#define N1SZ    45056
#define N2SZ    4096
#define F0SZ    25
#define F1SZ    10

typedef __attribute__((ext_vector_type(8))) short short8;
typedef __attribute__((ext_vector_type(4))) float f32x4;

__device__ inline unsigned short f2bfu(float x) {
    union { __hip_bfloat16 h; unsigned short u; } cv;
    cv.h = __float2bfloat16(x);
    return cv.u;
}

__device__ inline float bfu2f(unsigned short u) {
    union { float f; unsigned int u; } cv;
    cv.u = ((unsigned int)u) << 16;
    return cv.f;
}

// ---------------------------------------------------------------------------
// Kernel 1: weight prep — bf16, transposed to [N][K] so B-fragments are
// 16B-contiguous. W0T: [256 n][256 k] (k<128 -> Wn0, else Wr0).
// W1T: [48 n][512 k] (n>=47 zero-padded).
// ---------------------------------------------------------------------------
__global__ __launch_bounds__(256) void prep_w_kernel(
    const float* __restrict__ Wn0, const float* __restrict__ Wr0,
    const float* __restrict__ Wn1, const float* __restrict__ Wr1,
    __hip_bfloat16* __restrict__ W0T, __hip_bfloat16* __restrict__ W1T) {
    int tid = blockIdx.x * 256 + threadIdx.x;
    if (tid < 256 * 256) {
        int n = tid >> 8, k = tid & 255;
        float v = (k < INDIM) ? Wn0[(size_t)k * HIDDIM + n] : Wr0[(size_t)(k - INDIM) * HIDDIM + n];
        W0T[(size_t)n * 256 + k] = __float2bfloat16(v);
    }
    if (tid < 48 * 512) {
        int n = tid / 512, k = tid % 512;
        float v = 0.f;
        if (n < NCLSN) v = (k < HIDDIM) ? Wn1[(size_t)k * NCLSN + n] : Wr1[(size_t)(k - HIDDIM) * NCLSN + n];
        W1T[(size_t)n * 512 + k] = __float2bfloat16(v);
    }
}

// ---------------------------------------------------------------------------
// Kernel 2: FUSED layer 0.  Per block: 16 dst rows.
//   phase A: stage indices (stride loop — 400 entries > 256 threads!);
//            gather 16x25 neighbor rows (fp32, 512B each) + 16 self rows;
//            mean; convert bf16; write LDS A-tile [16][264pad]
//            (cols 0..127 = mean -> Wn0 part; 128..255 = self -> Wr0 part)
//   phase B: 4-wave MFMA GEMM (M=16, N=256, K=256) vs W0T (L2-hot),
//            +bias, ReLU, write H bf16 [45056][256].
// ---------------------------------------------------------------------------
__global__ __launch_bounds__(256) void fused_layer0_kernel(
    const float* __restrict__ node_feat, const int* __restrict__ gid0,
    const int* __restrict__ col0, const __hip_bfloat16* __restrict__ W0T,
    const float* __restrict__ b0, __hip_bfloat16* __restrict__ H) {
    __shared__ int sg[16 * F0SZ];
    __shared__ int sself[16];
    __shared__ alignas(16) short Atile[16 * 264];

    const int tid = threadIdx.x;
    const int rowbase = blockIdx.x * 16;

    // ---- stage two-level indices (400 sg entries, stride loop) ----
    for (int t = tid; t < 16 * F0SZ; t += 256) {
        int i = rowbase + t / F0SZ;
        int f = t % F0SZ;
        sg[t] = gid0[col0[(size_t)i * F0SZ + f]];
    }
    if (tid < 16) sself[tid] = gid0[rowbase + tid];
    __syncthreads();

    // ---- gather + mean: 16 rows x 16 lanes, each lane 8 dims ----
    {
        const int r = tid >> 4;        // 0..15
        const int l = tid & 15;        // 0..15, covers dims [l*8, l*8+8)
        float a0 = 0.f, a1 = 0.f, a2 = 0.f, a3 = 0.f, a4 = 0.f, a5 = 0.f, a6 = 0.f, a7 = 0.f;
        #pragma unroll
        for (int f = 0; f < F0SZ; ++f) {
            const float* p = node_feat + (size_t)sg[r * F0SZ + f] * INDIM + l * 8;
            float4 v0 = ((const float4*)p)[0];
            float4 v1 = ((const float4*)p)[1];
            a0 += v0.x; a1 += v0.y; a2 += v0.z; a3 += v0.w;
            a4 += v1.x; a5 += v1.y; a6 += v1.z; a7 += v1.w;
        }
        const float s = 1.0f / F0SZ;
        short8 m;
        m[0] = f2bfu(a0 * s); m[1] = f2bfu(a1 * s); m[2] = f2bfu(a2 * s); m[3] = f2bfu(a3 * s);
        m[4] = f2bfu(a4 * s); m[5] = f2bfu(a5 * s); m[6] = f2bfu(a6 * s); m[7] = f2bfu(a7 * s);
        *(short8*)&Atile[r * 264 + l * 8] = m;

        const float* sp = node_feat + (size_t)sself[r] * INDIM + l * 8;
        float4 s0 = ((const float4*)sp)[0];
        float4 s1 = ((const float4*)sp)[1];
        short8 se;
        se[0] = f2bfu(s0.x); se[1] = f2bfu(s0.y); se[2] = f2bfu(s0.z); se[3] = f2bfu(s0.w);
        se[4] = f2bfu(s1.x); se[5] = f2bfu(s1.y); se[6] = f2bfu(s1.z); se[7] = f2bfu(s1.w);
        *(short8*)&Atile[r * 264 + 128 + l * 8] = se;
    }
    __syncthreads();

    // ---- MFMA GEMM: wave w covers N cols [w*64, w*64+64) ----
    {
        const int wid = tid >> 6;
        const int lane = tid & 63;
        const int l15 = lane & 15;
        const int g = lane >> 4;
        const int nbase = wid * 64;
        const short* B = (const short*)W0T;
        f32x4 acc[4] = {};
        #pragma unroll
        for (int kk = 0; kk < 256; kk += 32) {
            const int ka = kk + g * 8;
            short8 a = *(const short8*)&Atile[l15 * 264 + ka];
            #pragma unroll
            for (int nt = 0; nt < 4; ++nt) {
                short8 b = *(const short8*)(B + (size_t)(nbase + nt * 16 + l15) * 256 + ka);
                acc[nt] = __builtin_amdgcn_mfma_f32_16x16x32_bf16(a, b, acc[nt], 0, 0, 0);
            }
        }
        #pragma unroll
        for (int nt = 0; nt < 4; ++nt) {
            const int col = nbase + nt * 16 + l15;
            const float bias = b0[col];
            #pragma unroll
            for (int r = 0; r < 4; ++r) {
                const int rr = rowbase + g * 4 + r;
                float v = acc[nt][r] + bias;
                v = v > 0.f ? v : 0.f;
                H[(size_t)rr * HIDDIM + col] = __float2bfloat16(v);
            }
        }
    }
}

// ---------------------------------------------------------------------------
// Kernel 3: FUSED layer 1.  512 threads/block, 16 dst rows/block (256 blocks).
//   phase A: gather 16x10 H rows (bf16, 512B each) + self; mean; write LDS
//            X-tile [16][520pad] (cols 0..255 mean, 256..511 self).
//   phase B: 8-wave MFMA, K-split 8x64, LDS reduce, +bias, write out fp32.
// ---------------------------------------------------------------------------
__global__ __launch_bounds__(512) void fused_layer1_kernel(
    const __hip_bfloat16* __restrict__ H, const int* __restrict__ col1,
    const __hip_bfloat16* __restrict__ W1T, const float* __restrict__ b1,
    float* __restrict__ out) {
    __shared__ int sc[16 * F1SZ];
    __shared__ alignas(16) short Xtile[16 * 520];
    __shared__ alignas(16) float red[8][16 * 48];

    const int tid = threadIdx.x;
    const int rowbase = blockIdx.x * 16;

    if (tid < 16 * F1SZ) {
        int i = rowbase + tid / F1SZ;
        int f = tid % F1SZ;
        sc[tid] = col1[(size_t)i * F1SZ + f];
    }
    __syncthreads();

    // ---- gather + mean: 16 rows x 32 lanes, each lane 8 dims ----
    {
        const int r = tid >> 5;        // 0..15
        const int l = tid & 31;        // 0..31, covers dims [l*8, l*8+8)
        const unsigned short* Hs = (const unsigned short*)H;
        float a0 = 0.f, a1 = 0.f, a2 = 0.f, a3 = 0.f, a4 = 0.f, a5 = 0.f, a6 = 0.f, a7 = 0.f;
        #pragma unroll
        for (int f = 0; f < F1SZ; ++f) {
            const unsigned short* p = Hs + (size_t)sc[r * F1SZ + f] * HIDDIM + l * 8;
            ushort4 v0 = ((const ushort4*)p)[0];
            ushort4 v1 = ((const ushort4*)p)[1];
            a0 += bfu2f(v0.x); a1 += bfu2f(v0.y); a2 += bfu2f(v0.z); a3 += bfu2f(v0.w);
            a4 += bfu2f(v1.x); a5 += bfu2f(v1.y); a6 += bfu2f(v1.z); a7 += bfu2f(v1.w);
        }
        const float s = 1.0f / F1SZ;
        short8 m;
        m[0] = f2bfu(a0 * s); m[1] = f2bfu(a1 * s); m[2] = f2bfu(a2 * s); m[3] = f2bfu(a3 * s);
        m[4] = f2bfu(a4 * s); m[5] = f2bfu(a5 * s); m[6] = f2bfu(a6 * s); m[7] = f2bfu(a7 * s);
        *(short8*)&Xtile[r * 520 + l * 8] = m;
        // self copy
        short8 se = *(const short8*)((const short*)Hs + (size_t)(rowbase + r) * HIDDIM + l * 8);
        *(short8*)&Xtile[r * 520 + 256 + l * 8] = se;
    }
    __syncthreads();

    // ---- MFMA: wave w takes K range [w*64, w*64+64) ----
    {
        const int wid = tid >> 6;      // 0..7
        const int lane = tid & 63;
        const int l15 = lane & 15;
        const int g = lane >> 4;
        const short* B = (const short*)W1T;
        f32x4 acc[3] = {};
        const int kbase = wid * 64;
        #pragma unroll
        for (int ks = 0; ks < 2; ++ks) {
            const int ka = kbase + ks * 32 + g * 8;
            short8 a = *(const short8*)&Xtile[l15 * 520 + ka];
            #pragma unroll
            for (int nt = 0; nt < 3; ++nt) {
                short8 b = *(const short8*)(B + (size_t)(nt * 16 + l15) * 512 + ka);
                acc[nt] = __builtin_amdgcn_mfma_f32_16x16x32_bf16(a, b, acc[nt], 0, 0, 0);
            }
        }
        #pragma unroll
        for (int nt = 0; nt < 3; ++nt)
            #pragma unroll
            for (int r = 0; r < 4; ++r)
                red[wid][(g * 4 + r) * 48 + nt * 16 + l15] = acc[nt][r];
    }
    __syncthreads();

    for (int t = tid; t < 16 * 48; t += 512) {
        int r = t / 48, c = t % 48;
        if (c < NCLSN) {
            float v = b1[c];
            #pragma unroll
            for (int w = 0; w < 8; ++w) v += red[w][t];
            out[(size_t)(rowbase + r) * NCLSN + c] = v;
        }
    }
}

// ---------------------------------------------------------------------------
extern "C" void kernel_launch(void* const* d_in, const int* in_sizes, int n_in,
                              void* d_out, int out_size, void* d_ws, size_t ws_size,
                              hipStream_t stream) {
    const float* node_feat = (const float*)d_in[0];
    const int*   gid0      = (const int*)d_in[1];
    const int*   col0      = (const int*)d_in[2];
    const int*   col1      = (const int*)d_in[3];
    const float* Wn0       = (const float*)d_in[4];
    const float* Wr0       = (const float*)d_in[5];
    const float* b0        = (const float*)d_in[6];
    const float* Wn1       = (const float*)d_in[7];
    const float* Wr1       = (const float*)d_in[8];
    const float* b1        = (const float*)d_in[9];

    char* ws = (char*)d_ws;
    // ws layout: H bf16 [45056][256] = 23,068,672 B ; W0T 131,072 B ; W1T 49,152 B
    __hip_bfloat16* H   = (__hip_bfloat16*)(ws);
    __hip_bfloat16* W0T = (__hip_bfloat16*)(ws + 23068672);
    __hip_bfloat16* W1T = (__hip_bfloat16*)(ws + 23068672 + 131072);
    float* out = (float*)d_out;

    hipLaunchKernelGGL(prep_w_kernel, dim3(256), dim3(256), 0, stream,
                       Wn0, Wr0, Wn1, Wr1, W0T, W1T);
    hipLaunchKernelGGL(fused_layer0_kernel, dim3(N1SZ / 16), dim3(256), 0, stream,
                       node_feat, gid0, col0, W0T, b0, H);
    hipLaunchKernelGGL(fused_layer1_kernel, dim3(N2SZ / 16), dim3(512), 0, stream,
                       H, col1, W1T, b1, out);
}